// Round 10
// baseline (676.020 us; speedup 1.0000x reference)
//
#include <hip/hip_runtime.h>
#include <hip/hip_bf16.h>
#include <stdint.h>

// LocalGConv: out[b,u,o] = relu( sum_s sum_v adj[s,u,v] * (sum_i x[b,v,i]*W[s,i,o]) + bias[o] )
// B=32768, V=43, DIN=DOUT=64, S=2. fp32 in/out; bf16 MFMA internally.
//
// v4 = v3 with the decomposition bug fixed. BLOCK owns each batch; the 4 waves split the
// o-dimension (wave wv -> o in [16wv,16wv+16)), so together they cover all 64 output columns
// (v3 had wave==batch AND wave==o-stripe: 3/4 of out never written, absmax 33.5).
// Kept from v3 (the desync theory, now correctly implemented):
//  - BARRIER-FREE main loop: each wave gathers its own x A-frags straight from global (the 4x
//    intra-block re-read of the same 11KB x[b] is L1/L2-absorbed; HBM bytes unchanged);
//    s_pre rows are wave-private (row = orow), s_a read-only -> no s_barrier, waves drift freely.
//  - register prefetch one batch deep (issue 12 dwordx4 at iter start, convert next iter).
//  - cvt_pk bf16 packing (v_cvt_pk_bf16_f32).
//  - LDS 23.3 KB, ~110 VGPR -> launch_bounds(256,4): 4 blocks/CU, 16 waves/CU.

#define BATCH 32768
#define NV 43
#define DIN 64
#define DOUT 64
#define NS 2
#define NWAVES 4

#define SP 104   // s_pre / s_acat row stride (bf16): 208B rows, 16B-aligned, 2-way-bank only

typedef __attribute__((ext_vector_type(8))) short short8;          // 8 bf16 = MFMA A/B frag
typedef __attribute__((ext_vector_type(4))) float f32x4;           // MFMA C/D frag
typedef __attribute__((ext_vector_type(4))) unsigned short ushort4_t;

// setup-path conversion (one-time): manual RNE
__device__ __forceinline__ unsigned short f2bf(float f) {
    union { float f; unsigned int u; } x;
    x.f = f;
    unsigned int r = x.u + 0x7FFFu + ((x.u >> 16) & 1u);  // RNE
    return (unsigned short)(r >> 16);
}

// hot-path conversion: paired so the compiler emits v_cvt_pk_bf16_f32 (RNE, same bits)
__device__ __forceinline__ unsigned int pk2(float lo, float hi) {
    __hip_bfloat162 h = __float22bfloat162_rn(make_float2(lo, hi));
    union { __hip_bfloat162 h; unsigned int u; } c;
    c.h = h;
    return c.u;
}

__device__ __forceinline__ short8 pack8(f32x4 a, f32x4 b) {
    union { short8 s; unsigned int u[4]; } r;
    r.u[0] = pk2(a[0], a[1]); r.u[1] = pk2(a[2], a[3]);
    r.u[2] = pk2(b[0], b[1]); r.u[3] = pk2(b[2], b[3]);
    return r.s;
}

__device__ __forceinline__ ushort4_t cvt4(f32x4 v) {
    union { ushort4_t v; unsigned int u[2]; } r;
    r.u[0] = pk2(v[0], v[1]); r.u[1] = pk2(v[2], v[3]);
    return r.v;
}

__global__ void __launch_bounds__(256, 4) lgconv_kernel(
    const float* __restrict__ xg,
    const float* __restrict__ adjg,
    const float* __restrict__ wg,
    const float* __restrict__ bg,
    float* __restrict__ outg)
{
    // pre_T merged: [o(64)][k = s*48+v, pad to SP]. Row o written+read ONLY by wave o>>4. 13312 B
    __shared__ __align__(16) unsigned short s_pre[DOUT * SP];
    // Acat: [u(48 pad)][k = s*48+v, pad to SP], zero-padded, read-only after setup. 9984 B
    __shared__ __align__(16) unsigned short s_a[48 * SP];

    const int tid  = threadIdx.x;
    const int wv   = tid >> 6;       // wave id 0..3 = o-stripe
    const int lane = tid & 63;
    const int quad = lane >> 4;
    const int l16  = lane & 15;

    // ---- init: zero pads (pre pad cols are never read; acat pads must be 0) ----
    for (int t = tid; t < DOUT * SP; t += 256) s_pre[t] = 0;
    for (int t = tid; t < 48 * SP; t += 256) s_a[t] = 0;
    __syncthreads();

    // ---- fill Acat: s_a[u][s*48+v] = adj[s][u][v] (bf16) ----
    for (int t = tid; t < NS * NV * NV; t += 256) {
        int s  = t / (NV * NV);
        int rc = t - s * NV * NV;
        int r  = rc / NV;
        int c  = rc - r * NV;
        s_a[r * SP + s * 48 + c] = f2bf(adjg[t]);
    }

    // ---- W B-frags for this wave's o-stripe: B[k = quad*8+j][n = l16] = W[s][i][wv*16+l16] ----
    short8 wfrag[NS][2];
    for (int s = 0; s < NS; ++s)
        for (int kc = 0; kc < 2; ++kc) {
            short8 f;
            #pragma unroll
            for (int j = 0; j < 8; ++j) {
                int i = kc * 32 + quad * 8 + j;
                f[j] = (short)f2bf(wg[(s * DIN + i) * DOUT + wv * 16 + l16]);
            }
            wfrag[s][kc] = f;
        }
    const float biasv = bg[wv * 16 + l16];
    __syncthreads();                                   // s_a ready; last barrier in the kernel

    const int orow = wv * 16 + l16;                    // this lane's o (stage1 C col / stage2 B col)

    // ---- per-lane x row pointers + validity (rows m >= 43 read nothing, frag = 0) ----
    // BLOCK owns batch blockIdx.x (+ gridDim.x steps); all 4 waves read the same x[b].
    const float* prow[3];
    bool mval[3];
    #pragma unroll
    for (int mt = 0; mt < 3; ++mt) {
        int m = mt * 16 + l16;
        mval[mt] = (m < NV);
        prow[mt] = xg + ((size_t)blockIdx.x * NV + m) * DIN + quad * 8;
    }

    // ---- prologue: prefetch first batch into registers ----
    f32x4 pf[3][2][2];
    #pragma unroll
    for (int mt = 0; mt < 3; ++mt)
        #pragma unroll
        for (int kc = 0; kc < 2; ++kc)
            #pragma unroll
            for (int h = 0; h < 2; ++h) {
                pf[mt][kc][h] = (f32x4){0.f, 0.f, 0.f, 0.f};
                if (mval[mt])
                    pf[mt][kc][h] = *(const f32x4*)(prow[mt] + kc * 32 + h * 4);
            }

    float* op = outg + (size_t)blockIdx.x * (NV * DOUT) + orow;
    const size_t xadv = (size_t)gridDim.x * NV * DIN;
    const size_t oadv = (size_t)gridDim.x * NV * DOUT;

    for (int b = blockIdx.x; b < BATCH; b += gridDim.x) {
        // ---- convert prefetched x -> A-frags: A[m = mt*16+l16][k = kc*32+quad*8+j] ----
        short8 afrag[3][2];
        #pragma unroll
        for (int mt = 0; mt < 3; ++mt)
            #pragma unroll
            for (int kc = 0; kc < 2; ++kc)
                afrag[mt][kc] = pack8(pf[mt][kc][0], pf[mt][kc][1]);

        // ---- issue next batch's loads (full iteration of work covers the latency) ----
        const bool hn = (b + (int)gridDim.x) < BATCH;
        #pragma unroll
        for (int mt = 0; mt < 3; ++mt) prow[mt] += xadv;
        #pragma unroll
        for (int mt = 0; mt < 3; ++mt)
            #pragma unroll
            for (int kc = 0; kc < 2; ++kc)
                #pragma unroll
                for (int h = 0; h < 2; ++h) {
                    pf[mt][kc][h] = (f32x4){0.f, 0.f, 0.f, 0.f};
                    if (hn && mval[mt])
                        pf[mt][kc][h] = *(const f32x4*)(prow[mt] + kc * 32 + h * 4);
                }

        // ---- stage1: pre[v, o] = x[b] @ W (this wave's o-stripe, both supports) ----
        #pragma unroll
        for (int s = 0; s < NS; ++s) {
            #pragma unroll
            for (int mt = 0; mt < 3; ++mt) {
                f32x4 c = {0.f, 0.f, 0.f, 0.f};
                c = __builtin_amdgcn_mfma_f32_16x16x32_bf16(afrag[mt][0], wfrag[s][0], c, 0, 0, 0);
                c = __builtin_amdgcn_mfma_f32_16x16x32_bf16(afrag[mt][1], wfrag[s][1], c, 0, 0, 0);
                // lane holds pre[v = mt*16+quad*4+r][o = orow]; store transposed, contiguous in k
                *(ushort4_t*)(&s_pre[orow * SP + s * 48 + mt * 16 + quad * 4]) = cvt4(c);
            }
        }
        __builtin_amdgcn_s_waitcnt(0xc07f);            // lgkmcnt(0): own pre stripe visible (wave-private)
        __builtin_amdgcn_sched_barrier(0);

        // ---- stage2: oacc = Acat @ preB (K = 96, zero-padded) ----
        f32x4 oacc[3];
        #pragma unroll
        for (int mt = 0; mt < 3; ++mt) oacc[mt] = (f32x4){0.f, 0.f, 0.f, 0.f};
        #pragma unroll
        for (int kc = 0; kc < 3; ++kc) {
            short8 bfr = *(const short8*)(&s_pre[orow * SP + kc * 32 + quad * 8]);
            #pragma unroll
            for (int mt = 0; mt < 3; ++mt) {
                short8 afr = *(const short8*)(&s_a[(mt * 16 + l16) * SP + kc * 32 + quad * 8]);
                oacc[mt] = __builtin_amdgcn_mfma_f32_16x16x32_bf16(afr, bfr, oacc[mt], 0, 0, 0);
            }
        }

        // ---- epilogue: bias + relu + store this wave's o-stripe ----
        #pragma unroll
        for (int mt = 0; mt < 3; ++mt) {
            #pragma unroll
            for (int r = 0; r < 4; ++r) {
                int u = mt * 16 + quad * 4 + r;
                if (u < NV)
                    op[(size_t)u * DOUT] = fmaxf(oacc[mt][r] + biasv, 0.f);
            }
        }
        op += oadv;
    }
}

extern "C" void kernel_launch(void* const* d_in, const int* in_sizes, int n_in,
                              void* d_out, int out_size, void* d_ws, size_t ws_size,
                              hipStream_t stream) {
    (void)in_sizes; (void)n_in; (void)d_ws; (void)ws_size; (void)out_size;
    const float* xg   = (const float*)d_in[0];
    const float* adjg = (const float*)d_in[1];
    const float* wg   = (const float*)d_in[2];
    const float* bg   = (const float*)d_in[3];
    float* outg = (float*)d_out;

    // 1024 blocks x 32 batches each; 4 blocks/CU resident, waves drift freely (no main-loop barrier).
    dim3 grid(1024), block(256);
    hipLaunchKernelGGL(lgconv_kernel, grid, block, 0, stream, xg, adjg, wg, bg, outg);
}

// Round 11
// 586.002 us; speedup vs baseline: 1.1536x; 1.1536x over previous
//
#include <hip/hip_runtime.h>
#include <hip/hip_bf16.h>
#include <stdint.h>

// LocalGConv: out[b,u,o] = relu( sum_s sum_v adj[s,u,v] * (sum_i x[b,v,i]*W[s,i,o]) + bias[o] )
// B=32768, V=43, DIN=DOUT=64, S=2. fp32 in/out; bf16 MFMA internally.
//
// v5 = v2 (the proven 591.4 us structure) + store-after-barrier.
// Post-mortem of v4 (676 us, kernel 267 us): dropping cooperative LDS staging turned the x-read
// into 4x-duplicated scattered 64B gathers (~960 VMEM txn/block-iter vs v2's ~364) -> per-CU
// L1/TA transaction throughput bound (HBM 28%, MFMA 6.6%, VALU 23%). Cooperative coalesced
// staging is the right structure; v2 was already ~85% of achievable BW.
// v5's single change vs v2: epilogue stores moved AFTER __syncthreads, so each iteration's
// out-stores get a full iteration to retire before the next barrier's vmcnt(0) drain, instead
// of all 4 waves eating the L2 write-ack latency at the same barrier they were issued before.
//  - block owns batch b (grid-stride); 4 waves split o (wave wv -> o in [16wv,16wv+16)).
//  - x staged cooperatively (coalesced f32x4 loads, cvt_pk to bf16), double-buffered in LDS,
//    prefetched one batch ahead (issue loads early, ds_write late).
//  - pre_T rows are wave-private by o-stripe -> only wave-local lgkmcnt(0) between stages.
//  - LDS 37.1 KB, ~110 VGPR -> launch_bounds(256,4): 4 blocks/CU.

#define BATCH 32768
#define NV 43
#define DIN 64
#define DOUT 64
#define NS 2
#define XEL (NV * DIN)        // 2752 floats per batch
#define NCHUNK (XEL / 4)      // 688 16-byte chunks per batch

#define SX 72                 // s_x row stride (bf16): 144B rows, 16B-aligned, 2-way-bank only (free)
#define SP 104                // s_pre / s_acat row stride: 208B rows, 16B-aligned

typedef __attribute__((ext_vector_type(8))) short short8;          // 8 bf16 = MFMA A/B frag
typedef __attribute__((ext_vector_type(4))) float f32x4;           // MFMA C/D frag
typedef __attribute__((ext_vector_type(4))) unsigned short ushort4_t;

// setup-path conversion (one-time): manual RNE
__device__ __forceinline__ unsigned short f2bf(float f) {
    union { float f; unsigned int u; } x;
    x.f = f;
    unsigned int r = x.u + 0x7FFFu + ((x.u >> 16) & 1u);  // RNE
    return (unsigned short)(r >> 16);
}

// hot-path conversion: paired so the compiler emits v_cvt_pk_bf16_f32 (RNE, same bits)
__device__ __forceinline__ unsigned int pk2(float lo, float hi) {
    __hip_bfloat162 h = __float22bfloat162_rn(make_float2(lo, hi));
    union { __hip_bfloat162 h; unsigned int u; } c;
    c.h = h;
    return c.u;
}

__device__ __forceinline__ ushort4_t cvt4(f32x4 v) {
    union { ushort4_t v; unsigned int u[2]; } r;
    r.u[0] = pk2(v[0], v[1]); r.u[1] = pk2(v[2], v[3]);
    return r.v;
}

__global__ void __launch_bounds__(256, 4) lgconv_kernel(
    const float* __restrict__ xg,
    const float* __restrict__ adjg,
    const float* __restrict__ wg,
    const float* __restrict__ bg,
    float* __restrict__ outg)
{
    // x[b] bf16, [48 rows v][SX], rows 43..47 stay zero forever. Double-buffered. 13824 B
    __shared__ __align__(16) unsigned short s_x[2][48 * SX];
    // pre_T merged: [o(64)][k = s*48+v, pad to SP]. Wave-private by o-stripe. 13312 B
    __shared__ __align__(16) unsigned short s_pre[DOUT * SP];
    // Acat: [u(48 pad)][k = s*48+v, pad to SP], zero-padded. 9984 B
    __shared__ __align__(16) unsigned short s_a[48 * SP];

    const int tid  = threadIdx.x;
    const int wv   = tid >> 6;       // wave id 0..3 = o-stripe
    const int lane = tid & 63;
    const int quad = lane >> 4;
    const int l16  = lane & 15;

    // ---- init: zero all LDS pads (x pad rows, acat pads, pre) ----
    {
        unsigned short* p = &s_x[0][0];
        for (int t = tid; t < 2 * 48 * SX; t += 256) p[t] = 0;
        for (int t = tid; t < DOUT * SP; t += 256) s_pre[t] = 0;
        for (int t = tid; t < 48 * SP; t += 256) s_a[t] = 0;
    }
    __syncthreads();

    // ---- fill Acat: s_a[u][s*48+v] = adj[s][u][v] (bf16) ----
    for (int t = tid; t < NS * NV * NV; t += 256) {
        int s  = t / (NV * NV);
        int rc = t - s * NV * NV;
        int r  = rc / NV;
        int c  = rc - r * NV;
        s_a[r * SP + s * 48 + c] = f2bf(adjg[t]);
    }

    // ---- W B-frags for this wave's o-stripe only: B[k = quad*8+j][n = l16] = W[s][i][wv*16+l16] ----
    short8 wfrag[NS][2];
    for (int s = 0; s < NS; ++s)
        for (int kc = 0; kc < 2; ++kc) {
            short8 f;
            #pragma unroll
            for (int j = 0; j < 8; ++j) {
                int i = kc * 32 + quad * 8 + j;
                f[j] = (short)f2bf(wg[(s * DIN + i) * DOUT + wv * 16 + l16]);
            }
            wfrag[s][kc] = f;
        }
    const float biasv = bg[wv * 16 + l16];

    // ---- prologue: stage first batch into buffer 0 (coalesced f32x4 -> bf16) ----
    {
        const float* src = xg + (size_t)blockIdx.x * XEL;
        #pragma unroll
        for (int c = 0; c < 3; ++c) {
            int flat = c * 256 + tid;                  // 16B-chunk index; chunk -> (v, i0)
            if (flat < NCHUNK) {
                f32x4 u = *(const f32x4*)(src + (size_t)flat * 4);
                *(ushort4_t*)(&s_x[0][(flat >> 4) * SX + (flat & 15) * 4]) = cvt4(u);
            }
        }
    }
    __syncthreads();

    const int orow = wv * 16 + l16;                    // this lane's o (stage1 C col / stage2 B col)
    int cur = 0;
    for (int b = blockIdx.x; b < BATCH; b += gridDim.x) {
        const int  bn = b + gridDim.x;
        const bool hn = (bn < BATCH);

        // ---- prefetch next batch's x into registers (issue EARLY; ds_write LATE) ----
        f32x4 pf0, pf1, pf2;
        const float* srcn = xg + (size_t)bn * XEL;
        if (hn) {
            pf0 = *(const f32x4*)(srcn + (size_t)(tid) * 4);
            pf1 = *(const f32x4*)(srcn + (size_t)(256 + tid) * 4);
            if (tid < NCHUNK - 512)
                pf2 = *(const f32x4*)(srcn + (size_t)(512 + tid) * 4);
        }

        // ---- stage1: pre[v, o] = x[b] @ Wcat (this wave's o-stripe, both supports) ----
        const unsigned short* xl = &s_x[cur][0];
        short8 afrag[3][2];                            // A[m = mt*16+l16][k = kc*32+quad*8+j]
        #pragma unroll
        for (int mt = 0; mt < 3; ++mt)
            #pragma unroll
            for (int kc = 0; kc < 2; ++kc)
                afrag[mt][kc] = *(const short8*)(xl + (mt * 16 + l16) * SX + kc * 32 + quad * 8);

        #pragma unroll
        for (int s = 0; s < NS; ++s) {
            #pragma unroll
            for (int mt = 0; mt < 3; ++mt) {
                f32x4 c = {0.f, 0.f, 0.f, 0.f};
                c = __builtin_amdgcn_mfma_f32_16x16x32_bf16(afrag[mt][0], wfrag[s][0], c, 0, 0, 0);
                c = __builtin_amdgcn_mfma_f32_16x16x32_bf16(afrag[mt][1], wfrag[s][1], c, 0, 0, 0);
                // lane holds pre[v = mt*16+quad*4+r][o = orow]; store transposed, contiguous in k
                *(ushort4_t*)(&s_pre[orow * SP + s * 48 + mt * 16 + quad * 4]) = cvt4(c);
            }
        }
        __builtin_amdgcn_s_waitcnt(0xc07f);            // lgkmcnt(0): own pre stripe visible (wave-private)
        __builtin_amdgcn_sched_barrier(0);

        // ---- stage2: oacc = Acat @ preB (K = 96, zero-padded) ----
        f32x4 oacc[3];
        #pragma unroll
        for (int mt = 0; mt < 3; ++mt) oacc[mt] = (f32x4){0.f, 0.f, 0.f, 0.f};
        #pragma unroll
        for (int kc = 0; kc < 3; ++kc) {
            short8 bfr = *(const short8*)(&s_pre[orow * SP + kc * 32 + quad * 8]);
            #pragma unroll
            for (int mt = 0; mt < 3; ++mt) {
                short8 afr = *(const short8*)(&s_a[(mt * 16 + l16) * SP + kc * 32 + quad * 8]);
                oacc[mt] = __builtin_amdgcn_mfma_f32_16x16x32_bf16(afr, bfr, oacc[mt], 0, 0, 0);
            }
        }

        // ---- write prefetched x into the other buffer (vmcnt wait lands here, late) ----
        if (hn) {
            unsigned short* xn = &s_x[cur ^ 1][0];
            *(ushort4_t*)(&xn[(tid >> 4) * SX + (tid & 15) * 4]) = cvt4(pf0);
            {
                int flat = 256 + tid;
                *(ushort4_t*)(&xn[(flat >> 4) * SX + (flat & 15) * 4]) = cvt4(pf1);
            }
            if (tid < NCHUNK - 512) {
                int flat = 512 + tid;
                *(ushort4_t*)(&xn[(flat >> 4) * SX + (flat & 15) * 4]) = cvt4(pf2);
            }
        }

        __syncthreads();                               // x[cur^1] ready; drains LAST iter's stores

        // ---- epilogue AFTER the barrier: stores get a full iteration to retire ----
        float* op = outg + (size_t)b * (NV * DOUT) + orow;
        #pragma unroll
        for (int mt = 0; mt < 3; ++mt) {
            #pragma unroll
            for (int r = 0; r < 4; ++r) {
                int u = mt * 16 + quad * 4 + r;
                if (u < NV)
                    op[(size_t)u * DOUT] = fmaxf(oacc[mt][r] + biasv, 0.f);
            }
        }
        cur ^= 1;
    }
}

extern "C" void kernel_launch(void* const* d_in, const int* in_sizes, int n_in,
                              void* d_out, int out_size, void* d_ws, size_t ws_size,
                              hipStream_t stream) {
    (void)in_sizes; (void)n_in; (void)d_ws; (void)ws_size; (void)out_size;
    const float* xg   = (const float*)d_in[0];
    const float* adjg = (const float*)d_in[1];
    const float* wg   = (const float*)d_in[2];
    const float* bg   = (const float*)d_in[3];
    float* outg = (float*)d_out;

    // 1024 blocks x 32 batches: 4 blocks/CU resident, one co-resident generation.
    dim3 grid(1024), block(256);
    hipLaunchKernelGGL(lgconv_kernel, grid, block, 0, stream, xg, adjg, wg, bg, outg);
}